// Round 8
// baseline (634.448 us; speedup 1.0000x reference)
//
#include <hip/hip_runtime.h>

// ---- sizes ----
// x: (1024,1,28,28); h1: (1024,32,14,14); h2: (1024,64,14,14)->12544; out: (1024,10)
#define NB 1024
#define TOTAL1 (NB*196)
#define SPS 200  // Sbuf pixel stride (196 real + 4 zero-pad; +8 guard at end)

// ws layout (float offsets) — identical to R4 + appended OW1P
#define WS_H1   0               // 6422528
#define WS_H2   6422528         // 12845056
#define WS_PART 19267584        // 4194304
#define WS_W1T  23461888        // 288    [kk][32]
#define WS_OW1T 23462176        // 162    (legacy, unused)
#define WS_W2T  23462338        // 18432  [k=ci*9+kk][co=64]
#define WS_OW2T 23480770        // 5184   [k=ci*9+j][c=18]
#define WS_OW1P 23485956        // 180    [j][20] padded for float4 reads
// end: 23486136 floats = 93.9 MB

// ---------------- weight transpose prep ----------------
__global__ __launch_bounds__(256) void prep(const float* __restrict__ w1,
                                            const float* __restrict__ ow1,
                                            const float* __restrict__ w2,
                                            const float* __restrict__ ow2,
                                            float* __restrict__ ws) {
  int i = blockIdx.x * 256 + threadIdx.x;
  if (i < 288)   { int co = i / 9,  kk = i % 9;   ws[WS_W1T  + kk * 32 + co] = w1[i]; }
  if (i < 162)   { int c  = i / 9,  j  = i % 9;   ws[WS_OW1T + j  * 18 + c ] = ow1[i];
                                                  ws[WS_OW1P + j  * 20 + c ] = ow1[i]; }
  if (i < 18432) { int co = i / 288, k = i % 288; ws[WS_W2T  + k  * 64 + co] = w2[i]; }
  if (i < 5184)  { int c  = i / 288, k = i % 288; ws[WS_OW2T + k  * 18 + c ] = ow2[i]; }
}

// ---------------- stage 1 v2: all weight reads via per-lane VMEM (L1-hot) ----------------
// Old version emitted ~1150 s_loads/thread interleaved with per-lane ds_reads -> every
// tap paid an lgkmcnt(0) drain against out-of-order SMEM (same defect as R1 stage2).
// vz (opaque VGPR zero) forces weights onto the VMEM path; w1/ow1/b1 total <2KB = L1-resident.
__global__ __launch_bounds__(256, 2) void stage1(const float* __restrict__ x,
                                                 const float* __restrict__ ob1,
                                                 const float* __restrict__ b1,
                                                 const float* __restrict__ ws,
                                                 float* __restrict__ h1) {
  __shared__ float ximg[3 * 784];
  int tid = threadIdx.x;
  int g0 = blockIdx.x * 256;
  int bfirst = g0 / 196;
  for (int idx = tid; idx < 3 * 784; idx += 256) {
    int img = idx / 784;
    int b = bfirst + img;
    ximg[idx] = (b < NB) ? x[b * 784 + (idx - img * 784)] : 0.f;
  }
  __syncthreads();
  int g = g0 + tid;
  if (g >= TOTAL1) return;
  int b = g / 196, p = g - b * 196;
  const float* im = ximg + (b - bfirst) * 784;
  int oy = p / 14, ox = p - (p / 14) * 14;

  int vz;  // opaque zero: defeats scalarization of weight loads
  asm volatile("v_mov_b32 %0, 0" : "=v"(vz));
  const float* __restrict__ w1v  = ws + WS_W1T  + vz;  // [kk][32]
  const float* __restrict__ owv  = ws + WS_OW1P + vz;  // [j][20]
  const float* __restrict__ b1v  = b1  + vz;
  const float* __restrict__ ob1v = ob1 + vz;

  float pooled[32];
#pragma unroll
  for (int co = 0; co < 32; ++co) pooled[co] = 0.f;

#pragma unroll 1
  for (int sub = 0; sub < 4; ++sub) {
    int y  = 2 * oy + (sub >> 1);
    int ix = 2 * ox + (sub & 1);
    float patch[9];
#pragma unroll
    for (int j = 0; j < 9; ++j) {
      int yy = y + j / 3 - 1, xc = ix + j % 3 - 1;
      bool ok = (yy >= 0) & (yy < 28) & (xc >= 0) & (xc < 28);
      patch[j] = ok ? im[yy * 28 + xc] : 0.f;
    }
    // offset conv: 18 channels, weights via VMEM float4
    float off[18];
    {
      float4 o0 = *(const float4*)(ob1v);
      float4 o1 = *(const float4*)(ob1v + 4);
      float4 o2 = *(const float4*)(ob1v + 8);
      float4 o3 = *(const float4*)(ob1v + 12);
      float2 o4 = *(const float2*)(ob1v + 16);
      off[0]=o0.x; off[1]=o0.y; off[2]=o0.z; off[3]=o0.w;
      off[4]=o1.x; off[5]=o1.y; off[6]=o1.z; off[7]=o1.w;
      off[8]=o2.x; off[9]=o2.y; off[10]=o2.z; off[11]=o2.w;
      off[12]=o3.x; off[13]=o3.y; off[14]=o3.z; off[15]=o3.w;
      off[16]=o4.x; off[17]=o4.y;
    }
#pragma unroll
    for (int j = 0; j < 9; ++j) {
      float v = patch[j];
      float4 wA = *(const float4*)(owv + j * 20);
      float4 wB = *(const float4*)(owv + j * 20 + 4);
      float4 wC = *(const float4*)(owv + j * 20 + 8);
      float4 wD = *(const float4*)(owv + j * 20 + 12);
      float2 wE = *(const float2*)(owv + j * 20 + 16);
      off[0]  = fmaf(v, wA.x, off[0]);  off[1]  = fmaf(v, wA.y, off[1]);
      off[2]  = fmaf(v, wA.z, off[2]);  off[3]  = fmaf(v, wA.w, off[3]);
      off[4]  = fmaf(v, wB.x, off[4]);  off[5]  = fmaf(v, wB.y, off[5]);
      off[6]  = fmaf(v, wB.z, off[6]);  off[7]  = fmaf(v, wB.w, off[7]);
      off[8]  = fmaf(v, wC.x, off[8]);  off[9]  = fmaf(v, wC.y, off[9]);
      off[10] = fmaf(v, wC.z, off[10]); off[11] = fmaf(v, wC.w, off[11]);
      off[12] = fmaf(v, wD.x, off[12]); off[13] = fmaf(v, wD.y, off[13]);
      off[14] = fmaf(v, wD.z, off[14]); off[15] = fmaf(v, wD.w, off[15]);
      off[16] = fmaf(v, wE.x, off[16]); off[17] = fmaf(v, wE.y, off[17]);
    }
    // deformable conv (Cin=1): a[32] init from b1 via VMEM
    float a[32];
#pragma unroll
    for (int q = 0; q < 8; ++q) {
      float4 bb = *(const float4*)(b1v + 4 * q);
      a[4*q+0]=bb.x; a[4*q+1]=bb.y; a[4*q+2]=bb.z; a[4*q+3]=bb.w;
    }
#pragma unroll
    for (int kk = 0; kk < 9; ++kk) {
      float py = (float)(y - 1 + kk / 3) + off[2 * kk];
      float px = (float)(ix - 1 + kk % 3) + off[2 * kk + 1];
      float y0f = floorf(py), x0f = floorf(px);
      float wy1 = py - y0f, wx1 = px - x0f;
      float wy0 = 1.f - wy1, wx0 = 1.f - wx1;
      int y0 = (int)y0f, x0 = (int)x0f;
      int y1 = y0 + 1, x1 = x0 + 1;
      bool vy0 = (y0 >= 0) & (y0 < 28), vy1 = (y1 >= 0) & (y1 < 28);
      bool vx0 = (x0 >= 0) & (x0 < 28), vx1 = (x1 >= 0) & (x1 < 28);
      float W00 = (vy0 & vx0) ? wy0 * wx0 : 0.f;
      float W01 = (vy0 & vx1) ? wy0 * wx1 : 0.f;
      float W10 = (vy1 & vx0) ? wy1 * wx0 : 0.f;
      float W11 = (vy1 & vx1) ? wy1 * wx1 : 0.f;
      int yc0 = min(max(y0, 0), 27), yc1 = min(max(y1, 0), 27);
      int xc0 = min(max(x0, 0), 27), xc1 = min(max(x1, 0), 27);
      float s = im[yc0 * 28 + xc0] * W00 + im[yc0 * 28 + xc1] * W01 +
                im[yc1 * 28 + xc0] * W10 + im[yc1 * 28 + xc1] * W11;
#pragma unroll
      for (int q = 0; q < 8; ++q) {
        float4 ww = *(const float4*)(w1v + kk * 32 + 4 * q);
        a[4*q+0] = fmaf(s, ww.x, a[4*q+0]);
        a[4*q+1] = fmaf(s, ww.y, a[4*q+1]);
        a[4*q+2] = fmaf(s, ww.z, a[4*q+2]);
        a[4*q+3] = fmaf(s, ww.w, a[4*q+3]);
      }
    }
#pragma unroll
    for (int co = 0; co < 32; ++co) pooled[co] += fmaxf(a[co], 0.f);
  }
#pragma unroll
  for (int co = 0; co < 32; ++co) h1[b * 6272 + co * 196 + p] = pooled[co] * 0.25f;
}

// ---------------- stage 2: R4/v4 verbatim (measured 215 us) ----------------
// LDS: imgT 25088B + Sbuf 25632B + offT 1664B = 52384B -> 3 blocks/CU (12 waves).
__global__ __launch_bounds__(256, 3) void stage2(const float* __restrict__ h1,
                                                 const float* __restrict__ ob2,
                                                 const float* __restrict__ b2,
                                                 const float* __restrict__ ws,
                                                 float* __restrict__ h2) {
  __shared__ float imgT[196 * 32];       // imgT[p*32 + ((ci+4p)&31)] = img[ci][p]
  __shared__ float Sbuf[32 * SPS + 8];   // S[ci*SPS + p]; +8 guard
  __shared__ float offT[2 * 208];        // current tap's (dy,dx)
  const float* __restrict__ w2t  = ws + WS_W2T;
  const float* __restrict__ ow2t = ws + WS_OW2T;
  int tid = threadIdx.x;
  int b = blockIdx.x;

  for (int e = tid; e < 6272; e += 256) {
    int ci = e / 196, p = e - ci * 196;
    imgT[p * 32 + ((ci + 4 * p) & 31)] = h1[b * 6272 + e];
  }

  int pp = tid;
  int spy = pp / 14, spx = pp - (pp / 14) * 14;

  int oc  = tid % 18;
  int opg = tid / 18;
  int op0 = opg * 16;
  bool oact = (tid < 234);
  float oacc[16];
#pragma unroll
  for (int i = 0; i < 16; ++i) oacc[i] = 0.f;

  for (int j = 0; j < 9; ++j) {
    __syncthreads();
    if (pp < 196) {
      int yy = spy + j / 3 - 1, xx = spx + j % 3 - 1;
      bool ok = (yy >= 0) & (yy < 14) & (xx >= 0) & (xx < 14);
      int idx = ok ? (yy * 14 + xx) : 0;
      const float* src = imgT + idx * 32;
      int rot = (4 * idx) & 31;
#pragma unroll
      for (int cg = 0; cg < 8; ++cg) {
        float4 v;
        if (ok) v = *(const float4*)(src + ((cg * 4 + rot) & 31));
        else    v = make_float4(0.f, 0.f, 0.f, 0.f);
        Sbuf[(cg * 4 + 0) * SPS + pp] = v.x;
        Sbuf[(cg * 4 + 1) * SPS + pp] = v.y;
        Sbuf[(cg * 4 + 2) * SPS + pp] = v.z;
        Sbuf[(cg * 4 + 3) * SPS + pp] = v.w;
      }
    } else if (pp < SPS) {
#pragma unroll
      for (int ci2 = 0; ci2 < 32; ++ci2) Sbuf[ci2 * SPS + pp] = 0.f;
    }
    __syncthreads();
    if (oact) {
      float wv[32];
#pragma unroll
      for (int ci2 = 0; ci2 < 32; ++ci2) wv[ci2] = ow2t[(ci2 * 9 + j) * 18 + oc];
      for (int ci2 = 0; ci2 < 32; ++ci2) {
        const float* srow = Sbuf + ci2 * SPS + op0;
        float w = wv[ci2];
#pragma unroll
        for (int t = 0; t < 4; ++t) {
          float4 s = *(const float4*)(srow + 4 * t);
          oacc[4 * t + 0] = fmaf(w, s.x, oacc[4 * t + 0]);
          oacc[4 * t + 1] = fmaf(w, s.y, oacc[4 * t + 1]);
          oacc[4 * t + 2] = fmaf(w, s.z, oacc[4 * t + 2]);
          oacc[4 * t + 3] = fmaf(w, s.w, oacc[4 * t + 3]);
        }
      }
    }
  }

  int cog = tid & 15, pg = tid >> 4;
  int co0 = cog * 4;
  int p0 = pg * 16;
  bool gact = (pg < 13);
  float acc[4][16];
  {
    float4 bb = *(const float4*)(b2 + co0);
    float bj[4] = {bb.x, bb.y, bb.z, bb.w};
#pragma unroll
    for (int jj = 0; jj < 4; ++jj)
#pragma unroll
      for (int i = 0; i < 16; ++i) acc[jj][i] = bj[jj];
  }
  float myob = oact ? ob2[oc] : 0.f;

  for (int kk = 0; kk < 9; ++kk) {
    __syncthreads();
    if (oact && (oc >> 1) == kk) {
      float* dst = offT + (oc & 1) * 208 + op0;
#pragma unroll
      for (int i = 0; i < 16; ++i) dst[i] = oacc[i] + myob;
    }
    __syncthreads();
    if (pp < 196) {
      float dyv = offT[pp];
      float dxv = offT[208 + pp];
      float pyv = (float)(spy - 1 + kk / 3) + dyv;
      float pxv = (float)(spx - 1 + kk % 3) + dxv;
      float y0f = floorf(pyv), x0f = floorf(pxv);
      float wy1 = pyv - y0f, wx1 = pxv - x0f;
      float wy0 = 1.f - wy1, wx0 = 1.f - wx1;
      int y0 = (int)y0f, x0 = (int)x0f;
      int y1 = y0 + 1, x1 = x0 + 1;
      bool vy0 = (y0 >= 0) & (y0 < 14), vy1 = (y1 >= 0) & (y1 < 14);
      bool vx0 = (x0 >= 0) & (x0 < 14), vx1 = (x1 >= 0) & (x1 < 14);
      float W00 = (vy0 & vx0) ? wy0 * wx0 : 0.f;
      float W01 = (vy0 & vx1) ? wy0 * wx1 : 0.f;
      float W10 = (vy1 & vx0) ? wy1 * wx0 : 0.f;
      float W11 = (vy1 & vx1) ? wy1 * wx1 : 0.f;
      int yc0 = min(max(y0, 0), 13), yc1 = min(max(y1, 0), 13);
      int xc0 = min(max(x0, 0), 13), xc1 = min(max(x1, 0), 13);
      int i00 = yc0 * 14 + xc0, i01 = yc0 * 14 + xc1;
      int i10 = yc1 * 14 + xc0, i11 = yc1 * 14 + xc1;
      const float* s00 = imgT + i00 * 32; int r00 = (4 * i00) & 31;
      const float* s01 = imgT + i01 * 32; int r01 = (4 * i01) & 31;
      const float* s10 = imgT + i10 * 32; int r10 = (4 * i10) & 31;
      const float* s11 = imgT + i11 * 32; int r11 = (4 * i11) & 31;
#pragma unroll
      for (int cg = 0; cg < 8; ++cg) {
        float4 a0 = *(const float4*)(s00 + ((cg * 4 + r00) & 31));
        float4 a1 = *(const float4*)(s01 + ((cg * 4 + r01) & 31));
        float4 a2 = *(const float4*)(s10 + ((cg * 4 + r10) & 31));
        float4 a3 = *(const float4*)(s11 + ((cg * 4 + r11) & 31));
        Sbuf[(cg * 4 + 0) * SPS + pp] = fmaf(W00, a0.x, fmaf(W01, a1.x, fmaf(W10, a2.x, W11 * a3.x)));
        Sbuf[(cg * 4 + 1) * SPS + pp] = fmaf(W00, a0.y, fmaf(W01, a1.y, fmaf(W10, a2.y, W11 * a3.y)));
        Sbuf[(cg * 4 + 2) * SPS + pp] = fmaf(W00, a0.z, fmaf(W01, a1.z, fmaf(W10, a2.z, W11 * a3.z)));
        Sbuf[(cg * 4 + 3) * SPS + pp] = fmaf(W00, a0.w, fmaf(W01, a1.w, fmaf(W10, a2.w, W11 * a3.w)));
      }
    } else if (pp < SPS) {
#pragma unroll
      for (int ci2 = 0; ci2 < 32; ++ci2) Sbuf[ci2 * SPS + pp] = 0.f;
    }
    __syncthreads();
    if (gact) {
      for (int cb = 0; cb < 32; cb += 4) {
        float4 w[4];
#pragma unroll
        for (int u = 0; u < 4; ++u)
          w[u] = *(const float4*)(w2t + ((cb + u) * 9 + kk) * 64 + co0);
#pragma unroll
        for (int u = 0; u < 4; ++u) {
          const float* srow = Sbuf + (cb + u) * SPS + p0;
          float4 s0 = *(const float4*)(srow);
          float4 s1 = *(const float4*)(srow + 4);
          float4 s2 = *(const float4*)(srow + 8);
          float4 s3 = *(const float4*)(srow + 12);
          float sv[16] = {s0.x, s0.y, s0.z, s0.w, s1.x, s1.y, s1.z, s1.w,
                          s2.x, s2.y, s2.z, s2.w, s3.x, s3.y, s3.z, s3.w};
          float wj[4] = {w[u].x, w[u].y, w[u].z, w[u].w};
#pragma unroll
          for (int jj = 0; jj < 4; ++jj)
#pragma unroll
            for (int i = 0; i < 16; ++i)
              acc[jj][i] = fmaf(wj[jj], sv[i], acc[jj][i]);
        }
      }
    }
  }

  if (gact) {
    float* __restrict__ orow = h2 + b * 12544 + co0 * 196 + p0;
#pragma unroll
    for (int jj = 0; jj < 4; ++jj) {
#pragma unroll
      for (int t = 0; t < 4; ++t) {
        if (p0 + 4 * t < 196) {
          float4 v;
          v.x = fmaxf(acc[jj][4 * t + 0], 0.f);
          v.y = fmaxf(acc[jj][4 * t + 1], 0.f);
          v.z = fmaxf(acc[jj][4 * t + 2], 0.f);
          v.w = fmaxf(acc[jj][4 * t + 3], 0.f);
          *(float4*)(orow + jj * 196 + 4 * t) = v;
        }
      }
    }
  }
}

// ---------------- fc1: K-split GEMM 1024x128, K=12544 -> partials[32][1024][128] ----------------
__global__ __launch_bounds__(256, 2) void fc1(const float* __restrict__ h2,
                                              const float* __restrict__ fw1,
                                              float* __restrict__ part) {
  __shared__ float a_s[56 * 72];   // [k][r]
  __shared__ float b_s[56 * 132];  // [k][c]
  int tid = threadIdx.x;
  int rb = (blockIdx.x & 15) * 64;
  int ks = blockIdx.x >> 4;
  int kbase = ks * 392;
  int c0 = (tid & 31) * 4;
  int r0 = (tid >> 5) * 8;

  float acc[8][4];
#pragma unroll
  for (int i = 0; i < 8; ++i)
#pragma unroll
    for (int j = 0; j < 4; ++j) acc[i][j] = 0.f;

  for (int ch = 0; ch < 7; ++ch) {
    int kb = kbase + ch * 56;
    __syncthreads();
#pragma unroll
    for (int t = 0; t < 14; ++t) {
      int idx = t * 256 + tid;
      int r = idx / 56, k = idx - r * 56;
      a_s[k * 72 + r] = h2[(rb + r) * 12544 + kb + k];
    }
#pragma unroll
    for (int t = 0; t < 28; ++t) {
      int idx = t * 256 + tid;
      int c = idx / 56, k = idx - c * 56;
      b_s[k * 132 + c] = fw1[c * 12544 + kb + k];
    }
    __syncthreads();
    for (int k = 0; k < 56; ++k) {
      float4 bv = *(const float4*)&b_s[k * 132 + c0];
      float4 av0 = *(const float4*)&a_s[k * 72 + r0];
      float4 av1 = *(const float4*)&a_s[k * 72 + r0 + 4];
      float av[8] = {av0.x, av0.y, av0.z, av0.w, av1.x, av1.y, av1.z, av1.w};
      float bj[4] = {bv.x, bv.y, bv.z, bv.w};
#pragma unroll
      for (int i = 0; i < 8; ++i)
#pragma unroll
        for (int j = 0; j < 4; ++j) acc[i][j] = fmaf(av[i], bj[j], acc[i][j]);
    }
  }
#pragma unroll
  for (int i = 0; i < 8; ++i) {
    int r = rb + r0 + i;
#pragma unroll
    for (int j = 0; j < 4; ++j)
      part[(ks * 1024 + r) * 128 + c0 + j] = acc[i][j];
  }
}

// ---------------- reduce partials + bias + relu + fc2 ----------------
__global__ __launch_bounds__(128) void fcfinal(const float* __restrict__ part,
                                               const float* __restrict__ fb1,
                                               const float* __restrict__ fw2,
                                               const float* __restrict__ fb2,
                                               float* __restrict__ out) {
  __shared__ float tbuf[128];
  int b = blockIdx.x, c = threadIdx.x;
  float s = fb1[c];
  for (int ks = 0; ks < 32; ++ks) s += part[(ks * 1024 + b) * 128 + c];
  tbuf[c] = fmaxf(s, 0.f);
  __syncthreads();
  if (c < 10) {
    float v = fb2[c];
#pragma unroll
    for (int k = 0; k < 128; ++k) v = fmaf(tbuf[k], fw2[c * 128 + k], v);
    out[b * 10 + c] = v;
  }
}

extern "C" void kernel_launch(void* const* d_in, const int* in_sizes, int n_in,
                              void* d_out, int out_size, void* d_ws, size_t ws_size,
                              hipStream_t stream) {
  const float* x   = (const float*)d_in[0];
  const float* ow1 = (const float*)d_in[1];
  const float* ob1 = (const float*)d_in[2];
  const float* w1  = (const float*)d_in[3];
  const float* b1  = (const float*)d_in[4];
  const float* ow2 = (const float*)d_in[5];
  const float* ob2 = (const float*)d_in[6];
  const float* w2  = (const float*)d_in[7];
  const float* b2  = (const float*)d_in[8];
  const float* fw1 = (const float*)d_in[9];
  const float* fb1 = (const float*)d_in[10];
  const float* fw2 = (const float*)d_in[11];
  const float* fb2 = (const float*)d_in[12];
  float* ws  = (float*)d_ws;
  float* out = (float*)d_out;

  prep<<<72, 256, 0, stream>>>(w1, ow1, w2, ow2, ws);
  stage1<<<784, 256, 0, stream>>>(x, ob1, b1, ws, ws + WS_H1);
  stage2<<<NB, 256, 0, stream>>>(ws + WS_H1, ob2, b2, ws, ws + WS_H2);
  fc1<<<512, 256, 0, stream>>>(ws + WS_H2, fw1, ws + WS_PART);
  fcfinal<<<1024, 128, 0, stream>>>(ws + WS_PART, fb1, fw2, fb2, out);
}

// Round 9
// 487.048 us; speedup vs baseline: 1.3026x; 1.3026x over previous
//
#include <hip/hip_runtime.h>

// ---- sizes ----
// x: (1024,1,28,28); h1: (1024,32,14,14); h2: (1024,64,14,14)->12544; out: (1024,10)
#define NB 1024
#define TOTAL1 (NB*196)
#define SPS 200  // Sbuf pixel stride

// ws layout (float offsets)
#define WS_H1   0               // 6422528
#define WS_H2   6422528         // 12845056
#define WS_PART 19267584        // 4194304
#define WS_W1T  23461888        // 288    [kk][32]
#define WS_OW1T 23462176        // 162    [j][18]
#define WS_W2T  23462338        // 18432  [k=ci*9+kk][co=64]
#define WS_OW2T 23480770        // 5184   [k=ci*9+j][18] (legacy)
#define WS_OW2P 23485956        // 5760   [k=ci*9+j][20] (16B-aligned, for stage2 VMEM reads)
// end: 23491716 floats = 94.0 MB

// ---------------- weight transpose prep ----------------
__global__ __launch_bounds__(256) void prep(const float* __restrict__ w1,
                                            const float* __restrict__ ow1,
                                            const float* __restrict__ w2,
                                            const float* __restrict__ ow2,
                                            float* __restrict__ ws) {
  int i = blockIdx.x * 256 + threadIdx.x;
  if (i < 288)   { int co = i / 9,  kk = i % 9;   ws[WS_W1T  + kk * 32 + co] = w1[i]; }
  if (i < 162)   { int c  = i / 9,  j  = i % 9;   ws[WS_OW1T + j  * 18 + c ] = ow1[i]; }
  if (i < 18432) { int co = i / 288, k = i % 288; ws[WS_W2T  + k  * 64 + co] = w2[i]; }
  if (i < 5184)  { int c  = i / 288, k = i % 288; ws[WS_OW2T + k  * 18 + c ] = ow2[i];
                                                  ws[WS_OW2P + k  * 20 + c ] = ow2[i]; }
}

// ---------------- stage 1: R4 original (offset conv + deform conv 1->32 + relu + pool) ----------------
__global__ __launch_bounds__(256, 2) void stage1(const float* __restrict__ x,
                                                 const float* __restrict__ ob1,
                                                 const float* __restrict__ b1,
                                                 const float* __restrict__ ws,
                                                 float* __restrict__ h1) {
  __shared__ float ximg[3 * 784];
  const float* __restrict__ w1t  = ws + WS_W1T;   // [kk][32]
  const float* __restrict__ ow1t = ws + WS_OW1T;  // [j][18]
  int tid = threadIdx.x;
  int g0 = blockIdx.x * 256;
  int bfirst = g0 / 196;
  for (int idx = tid; idx < 3 * 784; idx += 256) {
    int img = idx / 784;
    int b = bfirst + img;
    ximg[idx] = (b < NB) ? x[b * 784 + (idx - img * 784)] : 0.f;
  }
  __syncthreads();
  int g = g0 + tid;
  if (g >= TOTAL1) return;
  int b = g / 196, p = g - b * 196;
  const float* im = ximg + (b - bfirst) * 784;
  int oy = p / 14, ox = p - (p / 14) * 14;

  float pooled[32];
#pragma unroll
  for (int co = 0; co < 32; ++co) pooled[co] = 0.f;

  for (int sub = 0; sub < 4; ++sub) {
    int y  = 2 * oy + (sub >> 1);
    int ix = 2 * ox + (sub & 1);
    float patch[9];
#pragma unroll
    for (int j = 0; j < 9; ++j) {
      int yy = y + j / 3 - 1, xc = ix + j % 3 - 1;
      bool ok = (yy >= 0) & (yy < 28) & (xc >= 0) & (xc < 28);
      patch[j] = ok ? im[yy * 28 + xc] : 0.f;
    }
    float off[18];
#pragma unroll
    for (int c = 0; c < 18; ++c) off[c] = ob1[c];
#pragma unroll
    for (int j = 0; j < 9; ++j) {
      float v = patch[j];
#pragma unroll
      for (int c = 0; c < 18; ++c) off[c] = fmaf(v, ow1t[j * 18 + c], off[c]);
    }
    float a[32];
#pragma unroll
    for (int co = 0; co < 32; ++co) a[co] = b1[co];
#pragma unroll
    for (int kk = 0; kk < 9; ++kk) {
      float py = (float)(y - 1 + kk / 3) + off[2 * kk];
      float px = (float)(ix - 1 + kk % 3) + off[2 * kk + 1];
      float y0f = floorf(py), x0f = floorf(px);
      float wy1 = py - y0f, wx1 = px - x0f;
      float wy0 = 1.f - wy1, wx0 = 1.f - wx1;
      int y0 = (int)y0f, x0 = (int)x0f;
      int y1 = y0 + 1, x1 = x0 + 1;
      bool vy0 = (y0 >= 0) & (y0 < 28), vy1 = (y1 >= 0) & (y1 < 28);
      bool vx0 = (x0 >= 0) & (x0 < 28), vx1 = (x1 >= 0) & (x1 < 28);
      float W00 = (vy0 & vx0) ? wy0 * wx0 : 0.f;
      float W01 = (vy0 & vx1) ? wy0 * wx1 : 0.f;
      float W10 = (vy1 & vx0) ? wy1 * wx0 : 0.f;
      float W11 = (vy1 & vx1) ? wy1 * wx1 : 0.f;
      int yc0 = min(max(y0, 0), 27), yc1 = min(max(y1, 0), 27);
      int xc0 = min(max(x0, 0), 27), xc1 = min(max(x1, 0), 27);
      float s = im[yc0 * 28 + xc0] * W00 + im[yc0 * 28 + xc1] * W01 +
                im[yc1 * 28 + xc0] * W10 + im[yc1 * 28 + xc1] * W11;
#pragma unroll
      for (int co = 0; co < 32; ++co) a[co] = fmaf(s, w1t[kk * 32 + co], a[co]);
    }
#pragma unroll
    for (int co = 0; co < 32; ++co) pooled[co] += fmaxf(a[co], 0.f);
  }
#pragma unroll
  for (int co = 0; co < 32; ++co) h1[b * 6272 + co * 196 + p] = pooled[co] * 0.25f;
}

// ---------------- stage 2 v8: v6 low-LDS-traffic structure at cap 128 (256,2) ----------------
// Live set ~110 regs (acc 64 + oacc 18 + temps) fits cap=128 -> no spills (v6@84 spilled).
// LDS: imgT 25088 + Sbuf 12864 = 37952B -> 4 blocks/CU by LDS; VGPR ~120 -> 4 waves/SIMD.
__global__ __launch_bounds__(256, 2) void stage2(const float* __restrict__ h1,
                                                 const float* __restrict__ ob2,
                                                 const float* __restrict__ b2,
                                                 const float* __restrict__ ws,
                                                 float* __restrict__ h2) {
  __shared__ float imgT[196 * 32];      // imgT[p*32 + ((ci+4p)&31)] = img[ci][p]
  __shared__ float Sbuf[16 * SPS + 8];  // one 16-ci half of S[ci][p]
  const float* __restrict__ w2t  = ws + WS_W2T;
  const float* __restrict__ ow2t = ws + WS_OW2P;  // [k=ci*9+j][20]
  int tid = threadIdx.x;
  int b = blockIdx.x;

  // ---- phase 1: load image, transposed + bank-rotated ----
  for (int e = tid; e < 6272; e += 256) {
    int ci = e / 196, p = e - ci * 196;
    imgT[p * 32 + ((ci + 4 * p) & 31)] = h1[b * 6272 + e];
  }
  __syncthreads();

  int pp = tid;
  int spy = pp / 14, spx = pp - (pp / 14) * 14;

  int vz;  // opaque zero in a VGPR: keeps weight loads on the VMEM (vmcnt) path
  asm volatile("v_mov_b32 %0, 0" : "=v"(vz));

  // ---- phase 2: offset conv, pixel-major, barrier-free ----
  float oacc[18];
#pragma unroll
  for (int c = 0; c < 18; ++c) oacc[c] = 0.f;
  if (pp < 196) {
#pragma unroll 1
    for (int j = 0; j < 9; ++j) {
      int jy = j / 3, jx = j - jy * 3;
      int yy = spy + jy - 1, xx = spx + jx - 1;
      if (yy >= 0 && yy < 14 && xx >= 0 && xx < 14) {
        int idx = yy * 14 + xx;
        int rot = (4 * idx) & 31;
        const float* src = imgT + idx * 32;
        float4 R[8];
#pragma unroll
        for (int g = 0; g < 8; ++g)
          R[g] = *(const float4*)(src + ((g * 4 + rot) & 31));
        const float* wb = ow2t + j * 20 + vz;
#pragma unroll
        for (int ci = 0; ci < 32; ++ci) {
          float v = (ci & 3) == 0 ? R[ci >> 2].x : (ci & 3) == 1 ? R[ci >> 2].y
                  : (ci & 3) == 2 ? R[ci >> 2].z : R[ci >> 2].w;
          const float* wr = wb + ci * 180;
          float4 w0 = *(const float4*)(wr);
          float4 w1 = *(const float4*)(wr + 4);
          float4 w2v = *(const float4*)(wr + 8);
          float4 w3 = *(const float4*)(wr + 12);
          float2 w4 = *(const float2*)(wr + 16);
          oacc[0]  = fmaf(v, w0.x, oacc[0]);   oacc[1]  = fmaf(v, w0.y, oacc[1]);
          oacc[2]  = fmaf(v, w0.z, oacc[2]);   oacc[3]  = fmaf(v, w0.w, oacc[3]);
          oacc[4]  = fmaf(v, w1.x, oacc[4]);   oacc[5]  = fmaf(v, w1.y, oacc[5]);
          oacc[6]  = fmaf(v, w1.z, oacc[6]);   oacc[7]  = fmaf(v, w1.w, oacc[7]);
          oacc[8]  = fmaf(v, w2v.x, oacc[8]);  oacc[9]  = fmaf(v, w2v.y, oacc[9]);
          oacc[10] = fmaf(v, w2v.z, oacc[10]); oacc[11] = fmaf(v, w2v.w, oacc[11]);
          oacc[12] = fmaf(v, w3.x, oacc[12]);  oacc[13] = fmaf(v, w3.y, oacc[13]);
          oacc[14] = fmaf(v, w3.z, oacc[14]);  oacc[15] = fmaf(v, w3.w, oacc[15]);
          oacc[16] = fmaf(v, w4.x, oacc[16]);  oacc[17] = fmaf(v, w4.y, oacc[17]);
        }
      }
    }
#pragma unroll
    for (int c = 0; c < 18; ++c) oacc[c] += ob2[c];
  }

  // ---- phase 3: 9 taps x (sample-half -> GEMM-half) x 2 ----
  int cog = tid & 7, pg = tid >> 3;
  int co0 = cog * 8, p0 = pg * 8;
  bool gact = (pg < 25);
  float acc[8][8];
#pragma unroll
  for (int jc = 0; jc < 8; ++jc) {
    float bb = b2[co0 + jc];
#pragma unroll
    for (int ip = 0; ip < 8; ++ip) acc[jc][ip] = bb;
  }

#pragma unroll 1
  for (int kk = 0; kk < 9; ++kk) {
    float W00 = 0.f, W01 = 0.f, W10 = 0.f, W11 = 0.f;
    int i00 = 0, i01 = 0, i10 = 0, i11 = 0;
    int r00 = 0, r01 = 0, r10 = 0, r11 = 0;
    if (pp < 196) {
      float dyv = (kk==0)?oacc[0]:(kk==1)?oacc[2]:(kk==2)?oacc[4]:(kk==3)?oacc[6]
                 :(kk==4)?oacc[8]:(kk==5)?oacc[10]:(kk==6)?oacc[12]:(kk==7)?oacc[14]:oacc[16];
      float dxv = (kk==0)?oacc[1]:(kk==1)?oacc[3]:(kk==2)?oacc[5]:(kk==3)?oacc[7]
                 :(kk==4)?oacc[9]:(kk==5)?oacc[11]:(kk==6)?oacc[13]:(kk==7)?oacc[15]:oacc[17];
      int ky = kk / 3, kx = kk - ky * 3;
      float pyv = (float)(spy - 1 + ky) + dyv;
      float pxv = (float)(spx - 1 + kx) + dxv;
      float y0f = floorf(pyv), x0f = floorf(pxv);
      float wy1 = pyv - y0f, wx1 = pxv - x0f;
      float wy0 = 1.f - wy1, wx0 = 1.f - wx1;
      int y0 = (int)y0f, x0 = (int)x0f;
      int y1 = y0 + 1, x1 = x0 + 1;
      bool vy0 = (y0 >= 0) & (y0 < 14), vy1 = (y1 >= 0) & (y1 < 14);
      bool vx0 = (x0 >= 0) & (x0 < 14), vx1 = (x1 >= 0) & (x1 < 14);
      W00 = (vy0 & vx0) ? wy0 * wx0 : 0.f;
      W01 = (vy0 & vx1) ? wy0 * wx1 : 0.f;
      W10 = (vy1 & vx0) ? wy1 * wx0 : 0.f;
      W11 = (vy1 & vx1) ? wy1 * wx1 : 0.f;
      int yc0 = min(max(y0, 0), 13), yc1 = min(max(y1, 0), 13);
      int xc0 = min(max(x0, 0), 13), xc1 = min(max(x1, 0), 13);
      i00 = yc0 * 14 + xc0; i01 = yc0 * 14 + xc1;
      i10 = yc1 * 14 + xc0; i11 = yc1 * 14 + xc1;
      r00 = (4 * i00) & 31; r01 = (4 * i01) & 31;
      r10 = (4 * i10) & 31; r11 = (4 * i11) & 31;
    }
#pragma unroll 1
    for (int h = 0; h < 2; ++h) {
      __syncthreads();  // previous GEMM done with Sbuf
      if (pp < 196) {
#pragma unroll
        for (int cg = 0; cg < 4; ++cg) {
          int g = 4 * h + cg;
          float4 a0 = *(const float4*)(imgT + i00 * 32 + ((g * 4 + r00) & 31));
          float4 a1 = *(const float4*)(imgT + i01 * 32 + ((g * 4 + r01) & 31));
          float4 a2 = *(const float4*)(imgT + i10 * 32 + ((g * 4 + r10) & 31));
          float4 a3 = *(const float4*)(imgT + i11 * 32 + ((g * 4 + r11) & 31));
          Sbuf[(cg * 4 + 0) * SPS + pp] = fmaf(W00, a0.x, fmaf(W01, a1.x, fmaf(W10, a2.x, W11 * a3.x)));
          Sbuf[(cg * 4 + 1) * SPS + pp] = fmaf(W00, a0.y, fmaf(W01, a1.y, fmaf(W10, a2.y, W11 * a3.y)));
          Sbuf[(cg * 4 + 2) * SPS + pp] = fmaf(W00, a0.z, fmaf(W01, a1.z, fmaf(W10, a2.z, W11 * a3.z)));
          Sbuf[(cg * 4 + 3) * SPS + pp] = fmaf(W00, a0.w, fmaf(W01, a1.w, fmaf(W10, a2.w, W11 * a3.w)));
        }
      } else if (pp < SPS) {
#pragma unroll
        for (int ci2 = 0; ci2 < 16; ++ci2) Sbuf[ci2 * SPS + pp] = 0.f;
      }
      __syncthreads();  // Sbuf half ready
      if (gact) {
        int cibase = 16 * h;
#pragma unroll 4
        for (int ci = 0; ci < 16; ++ci) {
          const float* srow = Sbuf + ci * SPS + p0;
          float4 s0 = *(const float4*)(srow);
          float4 s1 = *(const float4*)(srow + 4);
          const float* wr = w2t + ((cibase + ci) * 9 + kk) * 64 + co0;
          float4 w0 = *(const float4*)(wr);
          float4 w1 = *(const float4*)(wr + 4);
          float sv[8] = {s0.x, s0.y, s0.z, s0.w, s1.x, s1.y, s1.z, s1.w};
          float wv[8] = {w0.x, w0.y, w0.z, w0.w, w1.x, w1.y, w1.z, w1.w};
#pragma unroll
          for (int jc = 0; jc < 8; ++jc)
#pragma unroll
            for (int ip = 0; ip < 8; ++ip)
              acc[jc][ip] = fmaf(wv[jc], sv[ip], acc[jc][ip]);
        }
      }
    }
  }

  // ---- phase 4: ReLU + float4 global stores ----
  if (gact) {
    float* __restrict__ orow = h2 + b * 12544 + co0 * 196 + p0;
#pragma unroll
    for (int jc = 0; jc < 8; ++jc) {
#pragma unroll
      for (int t = 0; t < 2; ++t) {
        if (p0 + 4 * t < 196) {
          float4 v;
          v.x = fmaxf(acc[jc][4 * t + 0], 0.f);
          v.y = fmaxf(acc[jc][4 * t + 1], 0.f);
          v.z = fmaxf(acc[jc][4 * t + 2], 0.f);
          v.w = fmaxf(acc[jc][4 * t + 3], 0.f);
          *(float4*)(orow + jc * 196 + 4 * t) = v;
        }
      }
    }
  }
}

// ---------------- fc1: K-split GEMM 1024x128, K=12544 -> partials[32][1024][128] ----------------
__global__ __launch_bounds__(256, 2) void fc1(const float* __restrict__ h2,
                                              const float* __restrict__ fw1,
                                              float* __restrict__ part) {
  __shared__ float a_s[56 * 72];   // [k][r]
  __shared__ float b_s[56 * 132];  // [k][c]
  int tid = threadIdx.x;
  int rb = (blockIdx.x & 15) * 64;
  int ks = blockIdx.x >> 4;
  int kbase = ks * 392;
  int c0 = (tid & 31) * 4;
  int r0 = (tid >> 5) * 8;

  float acc[8][4];
#pragma unroll
  for (int i = 0; i < 8; ++i)
#pragma unroll
    for (int j = 0; j < 4; ++j) acc[i][j] = 0.f;

  for (int ch = 0; ch < 7; ++ch) {
    int kb = kbase + ch * 56;
    __syncthreads();
#pragma unroll
    for (int t = 0; t < 14; ++t) {
      int idx = t * 256 + tid;
      int r = idx / 56, k = idx - r * 56;
      a_s[k * 72 + r] = h2[(rb + r) * 12544 + kb + k];
    }
#pragma unroll
    for (int t = 0; t < 28; ++t) {
      int idx = t * 256 + tid;
      int c = idx / 56, k = idx - c * 56;
      b_s[k * 132 + c] = fw1[c * 12544 + kb + k];
    }
    __syncthreads();
    for (int k = 0; k < 56; ++k) {
      float4 bv = *(const float4*)&b_s[k * 132 + c0];
      float4 av0 = *(const float4*)&a_s[k * 72 + r0];
      float4 av1 = *(const float4*)&a_s[k * 72 + r0 + 4];
      float av[8] = {av0.x, av0.y, av0.z, av0.w, av1.x, av1.y, av1.z, av1.w};
      float bj[4] = {bv.x, bv.y, bv.z, bv.w};
#pragma unroll
      for (int i = 0; i < 8; ++i)
#pragma unroll
        for (int j = 0; j < 4; ++j) acc[i][j] = fmaf(av[i], bj[j], acc[i][j]);
    }
  }
#pragma unroll
  for (int i = 0; i < 8; ++i) {
    int r = rb + r0 + i;
#pragma unroll
    for (int j = 0; j < 4; ++j)
      part[(ks * 1024 + r) * 128 + c0 + j] = acc[i][j];
  }
}

// ---------------- reduce partials + bias + relu + fc2 ----------------
__global__ __launch_bounds__(128) void fcfinal(const float* __restrict__ part,
                                               const float* __restrict__ fb1,
                                               const float* __restrict__ fw2,
                                               const float* __restrict__ fb2,
                                               float* __restrict__ out) {
  __shared__ float tbuf[128];
  int b = blockIdx.x, c = threadIdx.x;
  float s = fb1[c];
  for (int ks = 0; ks < 32; ++ks) s += part[(ks * 1024 + b) * 128 + c];
  tbuf[c] = fmaxf(s, 0.f);
  __syncthreads();
  if (c < 10) {
    float v = fb2[c];
#pragma unroll
    for (int k = 0; k < 128; ++k) v = fmaf(tbuf[k], fw2[c * 128 + k], v);
    out[b * 10 + c] = v;
  }
}

extern "C" void kernel_launch(void* const* d_in, const int* in_sizes, int n_in,
                              void* d_out, int out_size, void* d_ws, size_t ws_size,
                              hipStream_t stream) {
  const float* x   = (const float*)d_in[0];
  const float* ow1 = (const float*)d_in[1];
  const float* ob1 = (const float*)d_in[2];
  const float* w1  = (const float*)d_in[3];
  const float* b1  = (const float*)d_in[4];
  const float* ow2 = (const float*)d_in[5];
  const float* ob2 = (const float*)d_in[6];
  const float* w2  = (const float*)d_in[7];
  const float* b2  = (const float*)d_in[8];
  const float* fw1 = (const float*)d_in[9];
  const float* fb1 = (const float*)d_in[10];
  const float* fw2 = (const float*)d_in[11];
  const float* fb2 = (const float*)d_in[12];
  float* ws  = (float*)d_ws;
  float* out = (float*)d_out;

  prep<<<72, 256, 0, stream>>>(w1, ow1, w2, ow2, ws);
  stage1<<<784, 256, 0, stream>>>(x, ob1, b1, ws, ws + WS_H1);
  stage2<<<NB, 256, 0, stream>>>(ws + WS_H1, ob2, b2, ws, ws + WS_H2);
  fc1<<<512, 256, 0, stream>>>(ws + WS_H2, fw1, ws + WS_PART);
  fcfinal<<<1024, 128, 0, stream>>>(ws + WS_PART, fb1, fw2, fb2, out);
}